// Round 1
// 209.136 us; speedup vs baseline: 1.0464x; 1.0464x over previous
//
#include <hip/hip_runtime.h>

#define TPB 256
#define BPB 32   // blocks per batch -> 64*32 = 2048 blocks = 8 per CU = 32 waves/CU

typedef float floatx4 __attribute__((ext_vector_type(4)));

// Kernel 1: per-batch 4x4x4 histogram, histogramdd range semantics.
// v2: LDS-staged coalesced loads. Each tile = 768 float4 (1024 points).
// Threads load 3 lane-contiguous float4 (perfect coalescing), stage to LDS,
// read back their own 3-float4 point-triple via ds_read_b128.
// Each block writes its OWN 64-bin partial (full overwrite -> no init needed,
// no global atomics).
__global__ __launch_bounds__(TPB) void hist_kernel(const float* __restrict__ x,
                                                   unsigned* __restrict__ partials,
                                                   int Qv,   // number of complete float4-triples (= whole 4-point groups)
                                                   int F4,   // total float4s per batch
                                                   int N) {
    __shared__ unsigned h[64];
    __shared__ floatx4 stage[3 * TPB];   // 12 KB
    if (threadIdx.x < 64) h[threadIdx.x] = 0u;

    const int b = blockIdx.y;
    const int t = (int)threadIdx.x;
    const float* xb = x + (size_t)b * (size_t)N * 3u;
    const floatx4* xq = (const floatx4*)xb;   // batch base is 16B-aligned

    auto process = [&](float a, float bb, float c) {
        // drop points outside [-2,2] on any dim; x == 2.0 exactly -> last bin
        const bool inside = (fabsf(a) <= 2.0f) & (fabsf(bb) <= 2.0f) & (fabsf(c) <= 2.0f);
        const float f0 = fminf(fmaxf(floorf(a  + 2.0f), 0.0f), 3.0f);  // v_med3
        const float f1 = fminf(fmaxf(floorf(bb + 2.0f), 0.0f), 3.0f);
        const float f2 = fminf(fmaxf(floorf(c  + 2.0f), 0.0f), 3.0f);
        const int idx = (int)fmaf(f0, 16.0f, fmaf(f1, 4.0f, f2));      // exact small ints
        if (inside) atomicAdd(&h[idx], 1u);
    };

    const int nTiles = (Qv + TPB - 1) / TPB;
    for (int T = blockIdx.x; T < nTiles; T += BPB) {
        const int fbase = T * (3 * TPB);
        const int i0 = fbase + t;
        const int i1 = i0 + TPB;
        const int i2 = i1 + TPB;
        floatx4 v0 = {0.f, 0.f, 0.f, 0.f}, v1 = v0, v2 = v0;
        // fully coalesced: lane-contiguous float4 (1 KB per wave per instr)
        if (i0 < F4) v0 = __builtin_nontemporal_load(&xq[i0]);
        if (i1 < F4) v1 = __builtin_nontemporal_load(&xq[i1]);
        if (i2 < F4) v2 = __builtin_nontemporal_load(&xq[i2]);
        __syncthreads();             // prev tile's stage reads done; also covers h[] init
        stage[t]           = v0;
        stage[t + TPB]     = v1;
        stage[t + 2 * TPB] = v2;
        __syncthreads();
        const int q = T * TPB + t;   // this thread's 4-point group
        if (q < Qv) {
            const floatx4 p0 = stage[3 * t + 0];   // ds_read_b128, ~2-way banks (free)
            const floatx4 p1 = stage[3 * t + 1];
            const floatx4 p2 = stage[3 * t + 2];
            process(p0.x, p0.y, p0.z);
            process(p0.w, p1.x, p1.y);
            process(p1.z, p1.w, p2.x);
            process(p2.y, p2.z, p2.w);
        }
    }

    // Scalar tail points (empty when 3N % 4 == 0, as here): block x==0 only.
    if (blockIdx.x == 0) {
        for (int p = 4 * Qv + t; p < N; p += TPB)
            process(xb[3 * p], xb[3 * p + 1], xb[3 * p + 2]);
    }
    __syncthreads();

    if (t < 64) {
        // full overwrite of this block's slot (poison-safe, no init kernel)
        partials[((size_t)b * BPB + blockIdx.x) * 64 + t] = h[t];
    }
}

// Kernel 2: reduce partials + normalize + Linear(V=64 -> CLASSES=40).
// total in-range points per batch == sum of the 64 bins.
__global__ __launch_bounds__(64) void linear_kernel(const unsigned* __restrict__ partials,
                                                    const float* __restrict__ W,
                                                    const float* __restrict__ bias,
                                                    float* __restrict__ out) {
    const int b = blockIdx.x;
    const int v = threadIdx.x;

    unsigned s = 0u;
    #pragma unroll
    for (int p = 0; p < BPB; ++p)
        s += partials[((size_t)b * BPB + p) * 64 + v];   // coalesced across threads

    __shared__ float cnt[64];
    cnt[v] = (float)s;
    __syncthreads();

    const int c = v;
    if (c < 40) {
        float acc = 0.0f, tot = 0.0f;
        #pragma unroll
        for (int k = 0; k < 64; ++k) {
            const float cv = cnt[k];
            tot += cv;
            acc = fmaf(cv, W[c * 64 + k], acc);
        }
        out[b * 40 + c] = acc / tot + bias[c];
    }
}

extern "C" void kernel_launch(void* const* d_in, const int* in_sizes, int n_in,
                              void* d_out, int out_size, void* d_ws, size_t ws_size,
                              hipStream_t stream) {
    const float* x    = (const float*)d_in[0];   // [B, N, 3] fp32
    const float* W    = (const float*)d_in[1];   // [40, 64] fp32
    const float* bias = (const float*)d_in[2];   // [40] fp32
    float* out = (float*)d_out;                  // [64, 40] fp32

    const int B = 64;
    const int N = in_sizes[0] / (B * 3);         // 200000
    const int F4 = (N * 3) / 4;                  // float4s per batch (150000)
    const int Qv = F4 / 3;                       // complete 4-point groups (50000)

    unsigned* partials = (unsigned*)d_ws;        // B*BPB*64 uint32 = 512 KB

    dim3 grid(BPB, B);
    hist_kernel<<<grid, TPB, 0, stream>>>(x, partials, Qv, F4, N);
    linear_kernel<<<B, 64, 0, stream>>>(partials, W, bias, out);
}